// Round 23
// baseline (36.635 us; speedup 1.0000x reference)
//
#include <hip/hip_runtime.h>
#include <stdint.h>

#define NBOX 8192

// ws layout: float4 sbox[8192] (128 KB) then uint32_t flags[256] (1 KB).
// R23 = R22 with ONE change: suppress T=8 j-rows/thread (2048-row panels,
// 640 blocks) to halve per-pair LDS+loop overhead. Keeps R9/R16's proven
// shape: 256-thr blocks, 32-box LDS i-tile, stride-256 j reads, ALL
// per-thread j-state in NAMED SCALARS (rule #20). R11/R12's failed T=8 had
// 128-thr/16-box/2304-block shape — not repeated.

// ---------------------------------------------------------------------------
// Kernel 1: stable rank (desc score, asc index), LDS-free, uint4 sweep (R22).
// key = (~score_bits << 32) | index; rank(e) = #{i: key_i < key_e}.
// ---------------------------------------------------------------------------
__global__ __launch_bounds__(256) void nms_rank_kernel(
    const float4* __restrict__ bbox, const uint32_t* __restrict__ sb,
    float4* __restrict__ sbox, uint32_t* __restrict__ flags)
{
    const int tid = threadIdx.x;
    if (blockIdx.x == 0) flags[tid] = 0;     // 256 words

    const int lane = tid & 63;
    const int e0 = (int)blockIdx.x * 16 + (tid >> 6) * 4;  // wave's 4 elements

    uint32_t b0 = sb[e0 + 0], b1 = sb[e0 + 1], b2 = sb[e0 + 2], b3 = sb[e0 + 3];
    const uint64_t k0 = ((uint64_t)(~b0) << 32) | (uint32_t)(e0 + 0);
    const uint64_t k1 = ((uint64_t)(~b1) << 32) | (uint32_t)(e0 + 1);
    const uint64_t k2 = ((uint64_t)(~b2) << 32) | (uint32_t)(e0 + 2);
    const uint64_t k3 = ((uint64_t)(~b3) << 32) | (uint32_t)(e0 + 3);

    const uint4* sb4 = (const uint4*)sb;
    uint32_t c0 = 0, c1 = 0, c2 = 0, c3 = 0;
    #pragma unroll 8
    for (int s = 0; s < 32; ++s) {            // 32 dwordx4 loads = 8192 keys
        uint4 bv = sb4[s * 64 + lane];        // keys i0 .. i0+3, coalesced 16B
        int i0 = s * 256 + lane * 4;
        uint64_t ka = ((uint64_t)(~bv.x) << 32) | (uint32_t)(i0 + 0);
        uint64_t kb = ((uint64_t)(~bv.y) << 32) | (uint32_t)(i0 + 1);
        uint64_t kc = ((uint64_t)(~bv.z) << 32) | (uint32_t)(i0 + 2);
        uint64_t kd = ((uint64_t)(~bv.w) << 32) | (uint32_t)(i0 + 3);
        c0 += (ka < k0) ? 1u : 0u;  c0 += (kb < k0) ? 1u : 0u;
        c0 += (kc < k0) ? 1u : 0u;  c0 += (kd < k0) ? 1u : 0u;
        c1 += (ka < k1) ? 1u : 0u;  c1 += (kb < k1) ? 1u : 0u;
        c1 += (kc < k1) ? 1u : 0u;  c1 += (kd < k1) ? 1u : 0u;
        c2 += (ka < k2) ? 1u : 0u;  c2 += (kb < k2) ? 1u : 0u;
        c2 += (kc < k2) ? 1u : 0u;  c2 += (kd < k2) ? 1u : 0u;
        c3 += (ka < k3) ? 1u : 0u;  c3 += (kb < k3) ? 1u : 0u;
        c3 += (kc < k3) ? 1u : 0u;  c3 += (kd < k3) ? 1u : 0u;
    }
    #pragma unroll
    for (int off = 32; off; off >>= 1) {
        c0 += __shfl_down(c0, off);
        c1 += __shfl_down(c1, off);
        c2 += __shfl_down(c2, off);
        c3 += __shfl_down(c3, off);
    }
    if (lane == 0) {                          // unique ranks, dwordx4 stores
        sbox[c0] = bbox[e0 + 0];
        sbox[c1] = bbox[e0 + 1];
        sbox[c2] = bbox[e0 + 2];
        sbox[c3] = bbox[e0 + 3];
    }
}

// ---------------------------------------------------------------------------
// Kernel 2: T=8 tile suppression. Block (256 thr) = one 32-box i-tile (LDS)
// x one 2048-row j-panel (8 rows/thread, stride 256). Prefilter
// fmaf(ih, iw, -0.4110*ia) > 0.4110*ja (conservative: margin 7e-4*(ai+aj)
// >> f32 rounding; union >= 256 so reference 1e-9 clamp is identity;
// x-clamp dropped: non-overlap gives fmaf <= nta < 0 < tk). Exact path
// (rare, ctz walk) replicates reference IEEE f32 op order incl. division;
// __f*_rn blocks fma-contraction. Triangular grid: panels jp=0..3, tiles
// 64*(jp+1), cum 32*jp*(jp+1); 640 blocks.
// ---------------------------------------------------------------------------
#define PAIRQ(BJ, TK, CQ) { \
    float ty1 = fmaxf(bi.x, BJ.x), tx1 = fmaxf(bi.y, BJ.y); \
    float ty2 = fminf(bi.z, BJ.z), tx2 = fminf(bi.w, BJ.w); \
    float ih = fmaxf(ty2 - ty1, 0.0f), iw = tx2 - tx1; \
    CQ = CQ + CQ + ((fmaf(ih, iw, nta) > TK) ? 1u : 0u); }

#define DMASK(D) ((D) <= 0 ? 0u : ((D) >= 32 ? ~0u : ((1u << (D)) - 1u)))

#define EXACT_Q(BJ, CQ, QIDX) \
    if (CQ) { \
        const float ja = __fmul_rn(__fsub_rn(BJ.z, BJ.x), __fsub_rn(BJ.w, BJ.y)); \
        uint32_t m = CQ; bool h = false; \
        do { \
            int k = __builtin_ctz(m); m &= m - 1; \
            float4 bi = LB[k]; \
            float ia = __fmul_rn(__fsub_rn(bi.z, bi.x), __fsub_rn(bi.w, bi.y)); \
            float ty1 = fmaxf(bi.x, BJ.x), tx1 = fmaxf(bi.y, BJ.y); \
            float ty2 = fminf(bi.z, BJ.z), tx2 = fminf(bi.w, BJ.w); \
            float ih = fmaxf(__fsub_rn(ty2, ty1), 0.0f); \
            float iw = fmaxf(__fsub_rn(tx2, tx1), 0.0f); \
            float inter = __fmul_rn(ih, iw); \
            float un = __fsub_rn(__fadd_rn(ia, ja), inter); \
            float iou = inter / fmaxf(un, 1e-9f); \
            h |= (iou > 0.7f); \
        } while (m); \
        if (h) { \
            int j = jbase + (QIDX) * 256 + tid; \
            atomicOr(&flags[j >> 5], 1u << (j & 31)); \
        } \
    }

__global__ __launch_bounds__(256, 4) void nms_suppress_kernel(
    const float4* __restrict__ sbox, uint32_t* __restrict__ flags)
{
    __shared__ float4 LB[32];                // i-tile boxes (512 B)
    __shared__ float  LNT[32];               // -0.4110f * area_i

    const int tid = threadIdx.x;
    const int b = (int)blockIdx.x;

    int jp = 0;                               // panel walk (<=3 iters)
    while (32 * (jp + 1) * (jp + 2) <= b) ++jp;
    const int it = b - 32 * jp * (jp + 1);    // 0 .. 64*(jp+1)-1
    const int ibase = it * 32;                // <= 8160
    const int jbase = jp * 2048;

    if (tid < 32) {
        float4 bx = sbox[ibase + tid];
        LB[tid] = bx;
        LNT[tid] = -0.4110f * ((bx.z - bx.x) * (bx.w - bx.y));
    }

    const float4 bj0 = sbox[jbase + 0 * 256 + tid];
    const float4 bj1 = sbox[jbase + 1 * 256 + tid];
    const float4 bj2 = sbox[jbase + 2 * 256 + tid];
    const float4 bj3 = sbox[jbase + 3 * 256 + tid];
    const float4 bj4 = sbox[jbase + 4 * 256 + tid];
    const float4 bj5 = sbox[jbase + 5 * 256 + tid];
    const float4 bj6 = sbox[jbase + 6 * 256 + tid];
    const float4 bj7 = sbox[jbase + 7 * 256 + tid];
    const float tk0 = 0.4110f * ((bj0.z - bj0.x) * (bj0.w - bj0.y));
    const float tk1 = 0.4110f * ((bj1.z - bj1.x) * (bj1.w - bj1.y));
    const float tk2 = 0.4110f * ((bj2.z - bj2.x) * (bj2.w - bj2.y));
    const float tk3 = 0.4110f * ((bj3.z - bj3.x) * (bj3.w - bj3.y));
    const float tk4 = 0.4110f * ((bj4.z - bj4.x) * (bj4.w - bj4.y));
    const float tk5 = 0.4110f * ((bj5.z - bj5.x) * (bj5.w - bj5.y));
    const float tk6 = 0.4110f * ((bj6.z - bj6.x) * (bj6.w - bj6.y));
    const float tk7 = 0.4110f * ((bj7.z - bj7.x) * (bj7.w - bj7.y));
    __syncthreads();

    uint32_t c0 = 0, c1 = 0, c2 = 0, c3 = 0, c4 = 0, c5 = 0, c6 = 0, c7 = 0;
    #pragma unroll 8
    for (int ii = 31; ii >= 0; --ii) {       // descending: bit k <-> slot k
        const float4 bi = LB[ii];
        const float nta = LNT[ii];
        PAIRQ(bj0, tk0, c0)
        PAIRQ(bj1, tk1, c1)
        PAIRQ(bj2, tk2, c2)
        PAIRQ(bj3, tk3, c3)
        PAIRQ(bj4, tk4, c4)
        PAIRQ(bj5, tk5, c5)
        PAIRQ(bj6, tk6, c6)
        PAIRQ(bj7, tk7, c7)
    }

    // diagonal masking: valid slots k satisfy ibase+k < j (full tiles: all)
    const int dbase = jbase + tid - ibase;
    c0 &= DMASK(dbase + 0 * 256);
    c1 &= DMASK(dbase + 1 * 256);
    c2 &= DMASK(dbase + 2 * 256);
    c3 &= DMASK(dbase + 3 * 256);
    c4 &= DMASK(dbase + 4 * 256);
    c5 &= DMASK(dbase + 5 * 256);
    c6 &= DMASK(dbase + 6 * 256);
    c7 &= DMASK(dbase + 7 * 256);

    if (c0 | c1 | c2 | c3 | c4 | c5 | c6 | c7) {
        EXACT_Q(bj0, c0, 0)
        EXACT_Q(bj1, c1, 1)
        EXACT_Q(bj2, c2, 2)
        EXACT_Q(bj3, c3, 3)
        EXACT_Q(bj4, c4, 4)
        EXACT_Q(bj5, c5, 5)
        EXACT_Q(bj6, c6, 6)
        EXACT_Q(bj7, c7, 7)
    }
}

// ---------------------------------------------------------------------------
// Kernel 3: masked float4 write of sorted boxes.
// ---------------------------------------------------------------------------
__global__ __launch_bounds__(256) void nms_write_kernel(
    const float4* __restrict__ sbox, const uint32_t* __restrict__ flags,
    float4* __restrict__ out)
{
    int j = blockIdx.x * 256 + threadIdx.x;
    bool sup = (flags[j >> 5] >> (j & 31)) & 1u;
    float4 v = sbox[j];
    if (sup) { v.x = 0.0f; v.y = 0.0f; v.z = 0.0f; v.w = 0.0f; }
    out[j] = v;
}

extern "C" void kernel_launch(void* const* d_in, const int* in_sizes, int n_in,
                              void* d_out, int out_size, void* d_ws, size_t ws_size,
                              hipStream_t stream) {
    const float4*   bbox  = (const float4*)d_in[0];    // (8192,4) f32
    const uint32_t* sbits = (const uint32_t*)d_in[1];  // (8192,)  f32 bits
    float4* out = (float4*)d_out;                      // (8192,4) f32
    float4* sbox = (float4*)d_ws;                      // 128 KB
    uint32_t* flags = (uint32_t*)((char*)d_ws + NBOX * 16);  // 1 KB

    hipLaunchKernelGGL(nms_rank_kernel, dim3(NBOX / 16), dim3(256), 0, stream,
                       bbox, sbits, sbox, flags);
    // triangular tile grid: sum_{jp=0..3} 64*(jp+1) = 640 blocks of 256 thr
    hipLaunchKernelGGL(nms_suppress_kernel, dim3(640), dim3(256), 0, stream,
                       sbox, flags);
    hipLaunchKernelGGL(nms_write_kernel, dim3(NBOX / 256), dim3(256), 0, stream,
                       sbox, flags, out);
}

// Round 24
// 31.078 us; speedup vs baseline: 1.1788x; 1.1788x over previous
//
#include <hip/hip_runtime.h>
#include <stdint.h>

#define NBOX 8192

// ws layout: float4 sbox[8192] (128 KB) then uint32_t flags[256] (1 KB).
// R24 = R22 (best, 31.1us) with ONE change: suppress __launch_bounds__(256,8)
// so all 1152 identical-cost blocks are co-resident (4/CU leaves a 128-block
// second generation = ~44% idle tail). First CLEAN test of (256,8): R18/R19's
// regressions were confounded with the removed racy fused-write.

// ---------------------------------------------------------------------------
// Kernel 1: stable rank (desc score, asc index), LDS-free, uint4 sweep (R22).
// key = (~score_bits << 32) | index; rank(e) = #{i: key_i < key_e}
//   == jnp.argsort(-score) stable order (scores >= 0 -> bits monotone; keys
//   unique). Wave owns 4 elements; 32 dwordx4 loads (4 keys each), coalesced.
// Block 0 zeroes the flag bitmap (graph replay safe).
// ---------------------------------------------------------------------------
__global__ __launch_bounds__(256) void nms_rank_kernel(
    const float4* __restrict__ bbox, const uint32_t* __restrict__ sb,
    float4* __restrict__ sbox, uint32_t* __restrict__ flags)
{
    const int tid = threadIdx.x;
    if (blockIdx.x == 0) flags[tid] = 0;     // 256 words

    const int lane = tid & 63;
    const int e0 = (int)blockIdx.x * 16 + (tid >> 6) * 4;  // wave's 4 elements

    uint32_t b0 = sb[e0 + 0], b1 = sb[e0 + 1], b2 = sb[e0 + 2], b3 = sb[e0 + 3];
    const uint64_t k0 = ((uint64_t)(~b0) << 32) | (uint32_t)(e0 + 0);
    const uint64_t k1 = ((uint64_t)(~b1) << 32) | (uint32_t)(e0 + 1);
    const uint64_t k2 = ((uint64_t)(~b2) << 32) | (uint32_t)(e0 + 2);
    const uint64_t k3 = ((uint64_t)(~b3) << 32) | (uint32_t)(e0 + 3);

    const uint4* sb4 = (const uint4*)sb;
    uint32_t c0 = 0, c1 = 0, c2 = 0, c3 = 0;
    #pragma unroll 8
    for (int s = 0; s < 32; ++s) {            // 32 dwordx4 loads = 8192 keys
        uint4 bv = sb4[s * 64 + lane];        // keys i0 .. i0+3, coalesced 16B
        int i0 = s * 256 + lane * 4;
        uint64_t ka = ((uint64_t)(~bv.x) << 32) | (uint32_t)(i0 + 0);
        uint64_t kb = ((uint64_t)(~bv.y) << 32) | (uint32_t)(i0 + 1);
        uint64_t kc = ((uint64_t)(~bv.z) << 32) | (uint32_t)(i0 + 2);
        uint64_t kd = ((uint64_t)(~bv.w) << 32) | (uint32_t)(i0 + 3);
        c0 += (ka < k0) ? 1u : 0u;  c0 += (kb < k0) ? 1u : 0u;
        c0 += (kc < k0) ? 1u : 0u;  c0 += (kd < k0) ? 1u : 0u;
        c1 += (ka < k1) ? 1u : 0u;  c1 += (kb < k1) ? 1u : 0u;
        c1 += (kc < k1) ? 1u : 0u;  c1 += (kd < k1) ? 1u : 0u;
        c2 += (ka < k2) ? 1u : 0u;  c2 += (kb < k2) ? 1u : 0u;
        c2 += (kc < k2) ? 1u : 0u;  c2 += (kd < k2) ? 1u : 0u;
        c3 += (ka < k3) ? 1u : 0u;  c3 += (kb < k3) ? 1u : 0u;
        c3 += (kc < k3) ? 1u : 0u;  c3 += (kd < k3) ? 1u : 0u;
    }
    #pragma unroll
    for (int off = 32; off; off >>= 1) {
        c0 += __shfl_down(c0, off);
        c1 += __shfl_down(c1, off);
        c2 += __shfl_down(c2, off);
        c3 += __shfl_down(c3, off);
    }
    if (lane == 0) {                          // unique ranks, dwordx4 stores
        sbox[c0] = bbox[e0 + 0];
        sbox[c1] = bbox[e0 + 1];
        sbox[c2] = bbox[e0 + 2];
        sbox[c3] = bbox[e0 + 3];
    }
}

// ---------------------------------------------------------------------------
// Kernel 2: T=4 tile suppression — R22 loop verbatim, launch_bounds (256,8)
// (all 1152 blocks co-resident; LDS 640B, VGPR cap 64 >= used ~48).
// Block = one 32-box i-tile (LDS) x 1024 j-rows (4/thread, stride 256).
// Prefilter fmaf(ih, iw, -0.4110*ia) > 0.4110*ja, conservative (margin
// 7e-4*(ai+aj) >> f32 rounding; union >= 256 so reference 1e-9 clamp is
// identity; x-clamp dropped: non-overlap gives fmaf <= nta < 0 < tk).
// Exact path (rare, ctz walk) replicates reference IEEE f32 op order incl.
// division; __f*_rn blocks fma-contraction.
// ---------------------------------------------------------------------------
__global__ __launch_bounds__(256, 8) void nms_suppress_kernel(
    const float4* __restrict__ sbox, uint32_t* __restrict__ flags)
{
    __shared__ float4 LB[32];                // i-tile boxes (512 B)
    __shared__ float  LNT[32];               // -0.4110f * area_i

    const int tid = threadIdx.x;
    const int b = (int)blockIdx.x;

    int jb = (int)(sqrtf((float)b * 0.0625f + 0.25f) - 0.5f);
    while (16 * (jb + 1) * (jb + 2) <= b) ++jb;
    while (16 * jb * (jb + 1) > b) --jb;
    const int it = b - 16 * jb * (jb + 1);   // 0 .. 32*jb+31
    const int ibase = it * 32;               // <= 8160
    const int jbase = jb * 1024;

    if (tid < 32) {
        float4 bx = sbox[ibase + tid];
        LB[tid] = bx;
        LNT[tid] = -0.4110f * ((bx.z - bx.x) * (bx.w - bx.y));
    }

    const float4 bj0 = sbox[jbase + tid];
    const float4 bj1 = sbox[jbase + 256 + tid];
    const float4 bj2 = sbox[jbase + 512 + tid];
    const float4 bj3 = sbox[jbase + 768 + tid];
    const float tk0 = 0.4110f * ((bj0.z - bj0.x) * (bj0.w - bj0.y));
    const float tk1 = 0.4110f * ((bj1.z - bj1.x) * (bj1.w - bj1.y));
    const float tk2 = 0.4110f * ((bj2.z - bj2.x) * (bj2.w - bj2.y));
    const float tk3 = 0.4110f * ((bj3.z - bj3.x) * (bj3.w - bj3.y));
    __syncthreads();

    uint32_t c0 = 0, c1 = 0, c2 = 0, c3 = 0;
    #pragma unroll 8
    for (int ii = 31; ii >= 0; --ii) {       // descending: bit k <-> slot k
        const float4 bi = LB[ii];
        const float nta = LNT[ii];
        {
            float ty1 = fmaxf(bi.x, bj0.x), tx1 = fmaxf(bi.y, bj0.y);
            float ty2 = fminf(bi.z, bj0.z), tx2 = fminf(bi.w, bj0.w);
            float ih = fmaxf(ty2 - ty1, 0.0f), iw = tx2 - tx1;
            c0 = c0 + c0 + ((fmaf(ih, iw, nta) > tk0) ? 1u : 0u);
        }
        {
            float ty1 = fmaxf(bi.x, bj1.x), tx1 = fmaxf(bi.y, bj1.y);
            float ty2 = fminf(bi.z, bj1.z), tx2 = fminf(bi.w, bj1.w);
            float ih = fmaxf(ty2 - ty1, 0.0f), iw = tx2 - tx1;
            c1 = c1 + c1 + ((fmaf(ih, iw, nta) > tk1) ? 1u : 0u);
        }
        {
            float ty1 = fmaxf(bi.x, bj2.x), tx1 = fmaxf(bi.y, bj2.y);
            float ty2 = fminf(bi.z, bj2.z), tx2 = fminf(bi.w, bj2.w);
            float ih = fmaxf(ty2 - ty1, 0.0f), iw = tx2 - tx1;
            c2 = c2 + c2 + ((fmaf(ih, iw, nta) > tk2) ? 1u : 0u);
        }
        {
            float ty1 = fmaxf(bi.x, bj3.x), tx1 = fmaxf(bi.y, bj3.y);
            float ty2 = fminf(bi.z, bj3.z), tx2 = fminf(bi.w, bj3.w);
            float ih = fmaxf(ty2 - ty1, 0.0f), iw = tx2 - tx1;
            c3 = c3 + c3 + ((fmaf(ih, iw, nta) > tk3) ? 1u : 0u);
        }
    }

    // diagonal masking: valid slots are ii < j - ibase (full tiles -> ~0u)
    {
        int d0 = jbase + tid - ibase;
        int d1 = d0 + 256, d2 = d0 + 512, d3 = d0 + 768;
        c0 &= (d0 <= 0) ? 0u : ((d0 >= 32) ? ~0u : ((1u << d0) - 1u));
        c1 &= (d1 <= 0) ? 0u : ((d1 >= 32) ? ~0u : ((1u << d1) - 1u));
        c2 &= (d2 <= 0) ? 0u : ((d2 >= 32) ? ~0u : ((1u << d2) - 1u));
        c3 &= (d3 <= 0) ? 0u : ((d3 >= 32) ? ~0u : ((1u << d3) - 1u));
    }

    // rare exact path: reference fp op order, IEEE f32 division
    if (c0 | c1 | c2 | c3) {
        #pragma unroll
        for (int q = 0; q < 4; ++q) {
            uint32_t m = (q == 0) ? c0 : (q == 1) ? c1 : (q == 2) ? c2 : c3;
            if (!m) continue;
            const float4 bj = (q == 0) ? bj0 : (q == 1) ? bj1 : (q == 2) ? bj2 : bj3;
            const float ja = __fmul_rn(__fsub_rn(bj.z, bj.x), __fsub_rn(bj.w, bj.y));
            bool h = false;
            do {
                int k = __builtin_ctz(m); m &= m - 1;
                float4 bi = LB[k];
                float ia = __fmul_rn(__fsub_rn(bi.z, bi.x), __fsub_rn(bi.w, bi.y));
                float ty1 = fmaxf(bi.x, bj.x), tx1 = fmaxf(bi.y, bj.y);
                float ty2 = fminf(bi.z, bj.z), tx2 = fminf(bi.w, bj.w);
                float ih = fmaxf(__fsub_rn(ty2, ty1), 0.0f);
                float iw = fmaxf(__fsub_rn(tx2, tx1), 0.0f);
                float inter = __fmul_rn(ih, iw);
                float un = __fsub_rn(__fadd_rn(ia, ja), inter);
                float iou = inter / fmaxf(un, 1e-9f);
                h |= (iou > 0.7f);
            } while (m);
            if (h) {
                int j = jbase + q * 256 + tid;
                atomicOr(&flags[j >> 5], 1u << (j & 31));
            }
        }
    }
}

// ---------------------------------------------------------------------------
// Kernel 3: masked float4 write of sorted boxes.
// ---------------------------------------------------------------------------
__global__ __launch_bounds__(256) void nms_write_kernel(
    const float4* __restrict__ sbox, const uint32_t* __restrict__ flags,
    float4* __restrict__ out)
{
    int j = blockIdx.x * 256 + threadIdx.x;
    bool sup = (flags[j >> 5] >> (j & 31)) & 1u;
    float4 v = sbox[j];
    if (sup) { v.x = 0.0f; v.y = 0.0f; v.z = 0.0f; v.w = 0.0f; }
    out[j] = v;
}

extern "C" void kernel_launch(void* const* d_in, const int* in_sizes, int n_in,
                              void* d_out, int out_size, void* d_ws, size_t ws_size,
                              hipStream_t stream) {
    const float4*   bbox  = (const float4*)d_in[0];    // (8192,4) f32
    const uint32_t* sbits = (const uint32_t*)d_in[1];  // (8192,)  f32 bits
    float4* out = (float4*)d_out;                      // (8192,4) f32
    float4* sbox = (float4*)d_ws;                      // 128 KB
    uint32_t* flags = (uint32_t*)((char*)d_ws + NBOX * 16);  // 1 KB

    hipLaunchKernelGGL(nms_rank_kernel, dim3(NBOX / 16), dim3(256), 0, stream,
                       bbox, sbits, sbox, flags);
    // triangular tile grid: sum_{jb=0..7} (32*jb+32) = 1152 blocks of 256 thr
    hipLaunchKernelGGL(nms_suppress_kernel, dim3(1152), dim3(256), 0, stream,
                       sbox, flags);
    hipLaunchKernelGGL(nms_write_kernel, dim3(NBOX / 256), dim3(256), 0, stream,
                       sbox, flags, out);
}